// Round 2
// baseline (13283.287 us; speedup 1.0000x reference)
//
#include <hip/hip_runtime.h>

typedef unsigned short u16;
typedef unsigned int u32;
typedef unsigned long long u64;
typedef __attribute__((ext_vector_type(8))) short short8;
typedef __attribute__((ext_vector_type(4))) float f32x4;
typedef __attribute__((ext_vector_type(4))) float f4v;
typedef __attribute__((ext_vector_type(4))) unsigned short us4v;

#define TT 512
#define BB_ 32
#define II 2048
#define HH 1024

__device__ __forceinline__ u16 f2bf(float f) {
    u32 u = __float_as_uint(f);
    return (u16)((u + 0x7fffu + ((u >> 16) & 1u)) >> 16);
}
__device__ __forceinline__ float bf2f(u16 h) {
    return __uint_as_float(((u32)h) << 16);
}
__device__ __forceinline__ float ftanh(float x) {
    float e = __expf(2.f * x);
    return 1.f - 2.f / (e + 1.f);
}

// ---------------- fp32 -> bf16 conversion ----------------
__global__ __launch_bounds__(256) void f2bf_k(const float* __restrict__ s,
                                              u16* __restrict__ d, int n) {
    int i = (blockIdx.x * 256 + threadIdx.x) * 4;
    int stride = gridDim.x * 1024;
    for (; i < n; i += stride) {
        f4v v = *(const f4v*)(s + i);
        us4v o;
        o.x = f2bf(v.x); o.y = f2bf(v.y); o.z = f2bf(v.z); o.w = f2bf(v.w);
        *(us4v*)(d + i) = o;
    }
}

// ---------------- lens + flag init (dtype-robust mask read) ----------------
__global__ void prep(const unsigned char* __restrict__ mb, int* __restrict__ lens,
                     int* __restrict__ bar) {
    __shared__ int is8;
    int t = threadIdx.x;
    if (t == 0) is8 = 0;
    __syncthreads();
    for (int i = t; i < TT * BB_; i += 256) {
        if ((i & 3) && mb[i]) is8 = 1;   // benign race, same value
    }
    __syncthreads();
    int u8 = is8;
    if (t < BB_) {
        int c = 0;
        if (u8) {
            const unsigned char* r = mb + t * TT;
            for (int k = 0; k < TT; ++k) c += (r[k] == 0);
        } else {
            const int* r = (const int*)mb + t * TT;
            for (int k = 0; k < TT; ++k) c += (r[k] == 0);
        }
        c = (c < 0) ? 0 : (c > TT ? TT : c);
        lens[t] = c;
    }
    // zero flag slots (64 used, each padded to 32 ints / 128 B)
    for (int i = t; i < 256 * 32; i += 256) bar[i] = 0;
}

// ---------------- GEMM: G[m,n] = X[m,:] . W[n,:] + bi[n] + bh[n] ----------------
#define GM 16384
#define GN 4096
#define GK 2048

__device__ __forceinline__ void gload_lds16(const u16* g, u16* l) {
    __builtin_amdgcn_global_load_lds(
        (const __attribute__((address_space(1))) void*)g,
        (__attribute__((address_space(3))) void*)l, 16, 0, 0);
}

__global__ __launch_bounds__(256) void gemm_xw(
    const u16* __restrict__ X, const u16* __restrict__ W,
    const float* __restrict__ bi, const float* __restrict__ bh,
    u16* __restrict__ G)
{
    __shared__ u16 As[4096];
    __shared__ u16 Bs[4096];
    const int tid  = threadIdx.x;
    const int lane = tid & 63;
    const int r15  = lane & 15;
    const int quad = lane >> 4;
    const int wid  = tid >> 6;
    const int wr   = wid >> 1;
    const int wc   = wid & 1;
    const int m0   = blockIdx.y << 7;
    const int n0   = blockIdx.x << 7;

    f32x4 acc[4][4];
#pragma unroll
    for (int i = 0; i < 4; ++i)
#pragma unroll
        for (int j = 0; j < 4; ++j) acc[i][j] = (f32x4){0.f, 0.f, 0.f, 0.f};

    const int c0 = tid, c1 = 256 + tid;
    const int kq0 = c0 >> 7, row0 = c0 & 127;
    const int kq1 = c1 >> 7, row1 = c1 & 127;

    const u16* xA0 = X + (size_t)(m0 + row0) * GK + kq0 * 8;
    const u16* xA1 = X + (size_t)(m0 + row1) * GK + kq1 * 8;
    const u16* xB0 = W + (size_t)(n0 + row0) * GK + kq0 * 8;
    const u16* xB1 = W + (size_t)(n0 + row1) * GK + kq1 * 8;

    for (int kb = 0; kb < GK; kb += 32) {
        __syncthreads();
        gload_lds16(xA0 + kb, As + c0 * 8);
        gload_lds16(xA1 + kb, As + c1 * 8);
        gload_lds16(xB0 + kb, Bs + c0 * 8);
        gload_lds16(xB1 + kb, Bs + c1 * 8);
        __syncthreads();

        short8 a[4], b[4];
#pragma unroll
        for (int i = 0; i < 4; ++i)
            a[i] = *(const short8*)(As + (quad * 128 + wr * 64 + i * 16 + r15) * 8);
#pragma unroll
        for (int j = 0; j < 4; ++j)
            b[j] = *(const short8*)(Bs + (quad * 128 + wc * 64 + j * 16 + r15) * 8);
#pragma unroll
        for (int i = 0; i < 4; ++i)
#pragma unroll
            for (int j = 0; j < 4; ++j)
                acc[i][j] = __builtin_amdgcn_mfma_f32_16x16x32_bf16(a[i], b[j], acc[i][j], 0, 0, 0);
    }

#pragma unroll
    for (int j = 0; j < 4; ++j) {
        const int col = n0 + wc * 64 + j * 16 + r15;
        const float bias = bi[col] + bh[col];
#pragma unroll
        for (int i = 0; i < 4; ++i) {
            const int row = m0 + wr * 64 + i * 16 + quad * 4;
#pragma unroll
            for (int r = 0; r < 4; ++r)
                G[(size_t)(row + r) * GN + col] = f2bf(acc[i][j][r] + bias);
        }
    }
}

// ---------------- persistent LSTM layer (cooperative) ----------------
// 64 blocks x 1024 threads; block (dir, slice) owns 32 h-units.
// hbuf layout: [2 buf][2 dir][32 slice][32 batch][32 unit] bf16 -> each block
// publishes ONE contiguous 2 KB chunk per step.  h_s is staged into LDS once
// per block (coalesced sc1 loads), all 16 waves read fragments from LDS.
// Per-step L3 broadcast: 2 dir * 32 blk * 64 KB = 4 MB (was 33 MB).
#define NBLK 64

__global__ __launch_bounds__(1024, 1) void lstm_layer(
    int layer, int pbase,
    const u16* __restrict__ Whh,   // [4][4096][1024] bf16
    const u16* __restrict__ Gf,    // [16384][4096] bf16
    const u16* __restrict__ Gb,
    u16* __restrict__ ys0,         // layer0 output bf16 [16384][2048]
    float* __restrict__ out,       // d_out
    u16* __restrict__ hbuf,        // see above
    const int* __restrict__ lens,
    int* __restrict__ bar)         // flag slots * 32 ints
{
    const int blk   = blockIdx.x;
    const int dir   = blk & 1;
    const int slice = blk >> 1;     // 0..31
    const int j0    = slice << 5;   // 32 h-units per block
    const int tid   = threadIdx.x;
    const int lane  = tid & 63;
    const int r15   = lane & 15;
    const int quad  = lane >> 4;
    const int wid   = tid >> 6;     // 0..15
    const int bt    = wid & 1;      // batch half
    const int rt    = wid >> 1;     // gate-row group 0..7

    __shared__ u16 hls[32768];      // [128 kq][32 batch][8 k] = 64 KB
    __shared__ float ghh[32][132];  // [batch][128 gate rows], padded

    // Whh B-fragments resident in VGPRs for the whole kernel.
    const int nloc = rt * 16 + r15;                          // local gate row 0..127
    const int rowg = ((nloc >> 5) << 10) + j0 + (nloc & 31); // global gate row
    const u16* wp = Whh + ((size_t)(layer * 2 + dir) << 22) + ((size_t)rowg << 10) + quad * 8;
    short8 Bf[32];
#pragma unroll
    for (int f = 0; f < 32; ++f) Bf[f] = *(const short8*)(wp + f * 32);

    const int ub = tid & 31;       // unit within slice
    const int bb = tid >> 5;       // batch 0..31
    const int gu = j0 + ub;        // global h-unit
    const int len_b = lens[bb];
    float hreg = 0.f, creg = 0.f;

    int* myflag   = bar + ((dir << 5) + slice) * 32;
    int* pollflag = bar + ((dir << 5) + (tid & 31)) * 32;

    // staging map: thread -> (source slice ssl, batch sba)
    const int ssl = tid >> 5;
    const int sba = tid & 31;
    const u32 src_u16 = (u32)(ssl << 10) + (u32)(sba << 5);     // u16 offset in dir-plane
    char* const hls_b = (char*)hls + (size_t)(ssl << 11) + (size_t)(sba << 4);

    // zero h_0 (buffer 0) own chunk, write-through, then announce
    if ((ub & 1) == 0) {
        u32* hp = (u32*)(hbuf + (((size_t)dir) << 15) + ((size_t)slice << 10) + (bb << 5) + ub);
        __hip_atomic_store(hp, 0u, __ATOMIC_RELAXED, __HIP_MEMORY_SCOPE_AGENT);
    }
    asm volatile("s_waitcnt vmcnt(0)" ::: "memory");
    __syncthreads();
    if (tid == 0)
        __hip_atomic_store(myflag, pbase + 1, __ATOMIC_RELAXED, __HIP_MEMORY_SCOPE_AGENT);

    const u16* Gd = dir ? Gb : Gf;

    // prefetch gates for step 0
    int pcur = dir ? (len_b - 1) : 0;
    const u16* gp0 = Gd + (((size_t)pcur << 5) + bb) * 4096 + gu;
    u16 gvi = gp0[0], gvf = gp0[1024], gvg = gp0[2048], gvo = gp0[3072];

    for (int s = 0; s < TT; ++s) {
        // wait until every block of this direction has published h_s
        if (tid < 32) {
            const int target = pbase + s + 1;
            while (__hip_atomic_load(pollflag, __ATOMIC_RELAXED, __HIP_MEMORY_SCOPE_AGENT) < target)
                __builtin_amdgcn_s_sleep(1);
        }
        __syncthreads();

        // ---- stage h_s from coherent point into LDS (64 KB, read ONCE) ----
        {
            const u64* src = (const u64*)(hbuf + (((size_t)((s & 1) * 2 + dir)) << 15) + src_u16);
            u64 q[8];
#pragma unroll
            for (int k = 0; k < 8; ++k)
                q[k] = __hip_atomic_load(src + k, __ATOMIC_RELAXED, __HIP_MEMORY_SCOPE_AGENT);
#pragma unroll
            for (int j = 0; j < 4; ++j) {
                union { u64 a[2]; short8 v; } uu;
                uu.a[0] = q[2 * j]; uu.a[1] = q[2 * j + 1];
                *(short8*)(hls_b + j * 512) = uu.v;
            }
        }
        __syncthreads();

        // ---- h @ Whh^T : each wave 16 batches x 16 gate rows, full K=1024 ----
        f32x4 acc[4];
#pragma unroll
        for (int q2 = 0; q2 < 4; ++q2) acc[q2] = (f32x4){0.f, 0.f, 0.f, 0.f};
        char* const frag_b = (char*)hls + (size_t)((bt * 16 + r15) << 4) + (size_t)(quad << 9);
#pragma unroll
        for (int f = 0; f < 32; ++f) {
            short8 a = *(const short8*)(frag_b + (f << 11));
            acc[f & 3] = __builtin_amdgcn_mfma_f32_16x16x32_bf16(a, Bf[f], acc[f & 3], 0, 0, 0);
        }
        f32x4 ac = (acc[0] + acc[1]) + (acc[2] + acc[3]);
#pragma unroll
        for (int r = 0; r < 4; ++r)
            ghh[bt * 16 + quad * 4 + r][nloc] = ac[r];
        __syncthreads();

        // ---- elementwise: thread owns (batch bb, unit ub) ----
        float gi  = ghh[bb][ub]       + bf2f(gvi);
        float gf_ = ghh[bb][32 + ub]  + bf2f(gvf);
        float gg  = ghh[bb][64 + ub]  + bf2f(gvg);
        float go  = ghh[bb][96 + ub]  + bf2f(gvo);
        float si = 1.f / (1.f + __expf(-gi));
        float sf = 1.f / (1.f + __expf(-gf_));
        float sg = ftanh(gg);
        float so = 1.f / (1.f + __expf(-go));
        float cn = sf * creg + si * sg;
        float hn = so * ftanh(cn);
        bool valid = (s < len_b);
        if (valid) { creg = cn; hreg = hn; }

        // ---- publish h_{s+1}: one contiguous 2 KB chunk, write-through ----
        u32 hv = (u32)f2bf(hreg);
        u32 pv = (u32)__shfl_xor((int)hv, 1);
        if ((ub & 1) == 0) {
            u32 pk = hv | (pv << 16);
            u32* hp = (u32*)(hbuf + (((size_t)(((s + 1) & 1) * 2 + dir)) << 15)
                             + ((size_t)slice << 10) + (bb << 5) + ub);
            __hip_atomic_store(hp, pk, __ATOMIC_RELAXED, __HIP_MEMORY_SCOPE_AGENT);
        }
        asm volatile("s_waitcnt vmcnt(0)" ::: "memory");
        __syncthreads();
        if (tid == 0)
            __hip_atomic_store(myflag, pbase + s + 2, __ATOMIC_RELAXED, __HIP_MEMORY_SCOPE_AGENT);

        // ---- y-store (off critical path, after flag) ----
        float yv = valid ? hn : 0.f;
        size_t yoff = (((size_t)pcur << 5) + bb) * 2048 + ((size_t)dir << 10) + gu;
        if (layer == 0) ys0[yoff] = f2bf(yv);
        else            out[yoff] = yv;

        // ---- prefetch gates for s+1 (in flight during next poll) ----
        int sn = s + 1;
        if (sn < TT) {
            int pn = dir ? ((sn < len_b) ? (len_b - 1 - sn) : sn) : sn;
            const u16* gp = Gd + (((size_t)pn << 5) + bb) * 4096 + gu;
            gvi = gp[0]; gvf = gp[1024]; gvg = gp[2048]; gvo = gp[3072];
            pcur = pn;
        }
    }

    size_t hoff = (size_t)TT * BB_ * 2048 + (((size_t)(layer * 2 + dir) << 5) + bb) * 1024 + gu;
    out[hoff] = hreg;
    out[hoff + 4 * BB_ * HH] = creg;
}

// ---------------- host ----------------
extern "C" void kernel_launch(void* const* d_in, const int* in_sizes, int n_in,
                              void* d_out, int out_size, void* d_ws, size_t ws_size,
                              hipStream_t stream)
{
    const float* x    = (const float*)d_in[0];
    const unsigned char* mask = (const unsigned char*)d_in[1];
    const float* Wih  = (const float*)d_in[2];
    const float* Whh  = (const float*)d_in[3];
    const float* bih  = (const float*)d_in[4];
    const float* bhh  = (const float*)d_in[5];
    float* out = (float*)d_out;

    char* w = (char*)d_ws;
    size_t off = 0;
    auto take = [&](size_t bytes) {
        char* p = w + off;
        off = (off + bytes + 255) & ~(size_t)255;
        return p;
    };
    u16* xbf    = (u16*)take((size_t)33554432 * 2);   // x bf16; ALIASED as ys0 after layer-0 GEMMs
    u16* ysbf   = xbf;
    u16* wslice = (u16*)take((size_t)8388608 * 2);    // one Wih slice bf16, reused 4x
    u16* whhbf  = (u16*)take((size_t)16777216 * 2);   // Whh bf16
    u16* gf     = (u16*)take((size_t)67108864 * 2);   // gates fwd bf16
    u16* gb     = (u16*)take((size_t)67108864 * 2);   // gates bwd bf16
    u16* hbuf   = (u16*)take((size_t)131072 * 2);
    int* lens   = (int*)take(1024);
    int* bar    = (int*)take(65536);                  // flags * 128 B

    f2bf_k<<<2048, 256, 0, stream>>>(x,   xbf,   33554432);
    f2bf_k<<<2048, 256, 0, stream>>>(Whh, whhbf, 16777216);
    prep<<<1, 256, 0, stream>>>(mask, lens, bar);

    dim3 gg(32, 128);
    for (int l = 0; l < 2; ++l) {
        const u16* X = l ? ysbf : xbf;
        for (int d = 0; d < 2; ++d) {
            f2bf_k<<<1024, 256, 0, stream>>>(Wih + (size_t)(l * 2 + d) * 4096 * 2048,
                                             wslice, 8388608);
            gemm_xw<<<gg, 256, 0, stream>>>(X, wslice,
                                            bih + (l * 2 + d) * 4096,
                                            bhh + (l * 2 + d) * 4096,
                                            d ? gb : gf);
        }
        int layer = l;
        int pbase = l * (TT + 1);
        void* args[] = { &layer, &pbase, (void*)&whhbf, (void*)&gf, (void*)&gb,
                         (void*)&ysbf, (void*)&out, (void*)&hbuf, (void*)&lens, (void*)&bar };
        hipLaunchCooperativeKernel((void*)lstm_layer, dim3(NBLK), dim3(1024), args, 0, stream);
    }
    (void)in_sizes; (void)n_in; (void)out_size; (void)ws_size;
}

// Round 3
// 12295.585 us; speedup vs baseline: 1.0803x; 1.0803x over previous
//
#include <hip/hip_runtime.h>

typedef unsigned short u16;
typedef unsigned int u32;
typedef unsigned long long u64;
typedef __attribute__((ext_vector_type(8))) short short8;
typedef __attribute__((ext_vector_type(4))) float f32x4;
typedef __attribute__((ext_vector_type(4))) float f4v;
typedef __attribute__((ext_vector_type(4))) unsigned short us4v;

#define TT 512
#define BB_ 32
#define II 2048
#define HH 1024

__device__ __forceinline__ u16 f2bf(float f) {
    u32 u = __float_as_uint(f);
    return (u16)((u + 0x7fffu + ((u >> 16) & 1u)) >> 16);
}
__device__ __forceinline__ float bf2f(u16 h) {
    return __uint_as_float(((u32)h) << 16);
}
__device__ __forceinline__ float ftanh(float x) {
    float e = __expf(2.f * x);
    return 1.f - 2.f / (e + 1.f);
}

// ---------------- fp32 -> bf16 conversion ----------------
__global__ __launch_bounds__(256) void f2bf_k(const float* __restrict__ s,
                                              u16* __restrict__ d, int n) {
    int i = (blockIdx.x * 256 + threadIdx.x) * 4;
    int stride = gridDim.x * 1024;
    for (; i < n; i += stride) {
        f4v v = *(const f4v*)(s + i);
        us4v o;
        o.x = f2bf(v.x); o.y = f2bf(v.y); o.z = f2bf(v.z); o.w = f2bf(v.w);
        *(us4v*)(d + i) = o;
    }
}

// ---------------- lens + flag init (dtype-robust mask read) ----------------
__global__ void prep(const unsigned char* __restrict__ mb, int* __restrict__ lens,
                     int* __restrict__ bar) {
    __shared__ int is8;
    int t = threadIdx.x;
    if (t == 0) is8 = 0;
    __syncthreads();
    for (int i = t; i < TT * BB_; i += 256) {
        if ((i & 3) && mb[i]) is8 = 1;   // benign race, same value
    }
    __syncthreads();
    int u8 = is8;
    if (t < BB_) {
        int c = 0;
        if (u8) {
            const unsigned char* r = mb + t * TT;
            for (int k = 0; k < TT; ++k) c += (r[k] == 0);
        } else {
            const int* r = (const int*)mb + t * TT;
            for (int k = 0; k < TT; ++k) c += (r[k] == 0);
        }
        c = (c < 0) ? 0 : (c > TT ? TT : c);
        lens[t] = c;
    }
    // zero 256 flag slots, each padded to 32 ints (128 B)
    for (int i = t; i < 256 * 32; i += 256) bar[i] = 0;
}

// ---------------- GEMM: G[m,n] = X[m,:] . W[n,:] + bi[n] + bh[n] ----------------
#define GM 16384
#define GN 4096
#define GK 2048

__device__ __forceinline__ void gload_lds16(const u16* g, u16* l) {
    __builtin_amdgcn_global_load_lds(
        (const __attribute__((address_space(1))) void*)g,
        (__attribute__((address_space(3))) void*)l, 16, 0, 0);
}

__global__ __launch_bounds__(256) void gemm_xw(
    const u16* __restrict__ X, const u16* __restrict__ W,
    const float* __restrict__ bi, const float* __restrict__ bh,
    u16* __restrict__ G)
{
    __shared__ u16 As[4096];
    __shared__ u16 Bs[4096];
    const int tid  = threadIdx.x;
    const int lane = tid & 63;
    const int r15  = lane & 15;
    const int quad = lane >> 4;
    const int wid  = tid >> 6;
    const int wr   = wid >> 1;
    const int wc   = wid & 1;
    const int m0   = blockIdx.y << 7;
    const int n0   = blockIdx.x << 7;

    f32x4 acc[4][4];
#pragma unroll
    for (int i = 0; i < 4; ++i)
#pragma unroll
        for (int j = 0; j < 4; ++j) acc[i][j] = (f32x4){0.f, 0.f, 0.f, 0.f};

    const int c0 = tid, c1 = 256 + tid;
    const int kq0 = c0 >> 7, row0 = c0 & 127;
    const int kq1 = c1 >> 7, row1 = c1 & 127;

    const u16* xA0 = X + (size_t)(m0 + row0) * GK + kq0 * 8;
    const u16* xA1 = X + (size_t)(m0 + row1) * GK + kq1 * 8;
    const u16* xB0 = W + (size_t)(n0 + row0) * GK + kq0 * 8;
    const u16* xB1 = W + (size_t)(n0 + row1) * GK + kq1 * 8;

    for (int kb = 0; kb < GK; kb += 32) {
        __syncthreads();
        gload_lds16(xA0 + kb, As + c0 * 8);
        gload_lds16(xA1 + kb, As + c1 * 8);
        gload_lds16(xB0 + kb, Bs + c0 * 8);
        gload_lds16(xB1 + kb, Bs + c1 * 8);
        __syncthreads();

        short8 a[4], b[4];
#pragma unroll
        for (int i = 0; i < 4; ++i)
            a[i] = *(const short8*)(As + (quad * 128 + wr * 64 + i * 16 + r15) * 8);
#pragma unroll
        for (int j = 0; j < 4; ++j)
            b[j] = *(const short8*)(Bs + (quad * 128 + wc * 64 + j * 16 + r15) * 8);
#pragma unroll
        for (int i = 0; i < 4; ++i)
#pragma unroll
            for (int j = 0; j < 4; ++j)
                acc[i][j] = __builtin_amdgcn_mfma_f32_16x16x32_bf16(a[i], b[j], acc[i][j], 0, 0, 0);
    }

#pragma unroll
    for (int j = 0; j < 4; ++j) {
        const int col = n0 + wc * 64 + j * 16 + r15;
        const float bias = bi[col] + bh[col];
#pragma unroll
        for (int i = 0; i < 4; ++i) {
            const int row = m0 + wr * 64 + i * 16 + quad * 4;
#pragma unroll
            for (int r = 0; r < 4; ++r)
                G[(size_t)(row + r) * GN + col] = f2bf(acc[i][j][r] + bias);
        }
    }
}

// ---------------- persistent LSTM layer (cooperative) ----------------
// r1 geometry (256 blocks x 256 thr, block = (dir, slice of 8 h-units)).
// NEW: Whh slice lives in LDS (filled once, pre-swizzled to per-lane fragment
// order) -> guaranteed on-chip B-operands.  rocprof showed VGPR_Count=120 <
// 128 needed for Bf[32]: the compiler was re-fetching 32 KB/wave of Whh from
// L2 every step on the MFMA critical path.
#define NBLK 256

#define LOADC(dst, basef)                                                          \
  { _Pragma("unroll")                                                              \
    for (int f = 0; f < 8; ++f) {                                                  \
      const u64* hq = (const u64*)(hb + ((basef) + f) * 32 + quad * 8);            \
      union { u64 q[2]; short8 v; } uu;                                            \
      uu.q[0] = __hip_atomic_load(hq,     __ATOMIC_RELAXED, __HIP_MEMORY_SCOPE_AGENT); \
      uu.q[1] = __hip_atomic_load(hq + 1, __ATOMIC_RELAXED, __HIP_MEMORY_SCOPE_AGENT); \
      dst[f] = uu.v;                                                               \
    } }

#define MFMA8B(src, basef)                                                         \
  { _Pragma("unroll")                                                              \
    for (int f = 0; f < 8; ++f) {                                                  \
      short8 b = *(const short8*)((const char*)Bl + ((((basef) + f)) << 11) + bl_byte); \
      acc[((basef) + f) & 3] = __builtin_amdgcn_mfma_f32_16x16x32_bf16(            \
          src[f], b, acc[((basef) + f) & 3], 0, 0, 0);                             \
    } }

__global__ __launch_bounds__(256, 1) void lstm_layer(
    int layer, int pbase,
    const u16* __restrict__ Whh,   // [4][4096][1024] bf16
    const u16* __restrict__ Gf,    // [16384][4096] bf16
    const u16* __restrict__ Gb,
    u16* __restrict__ ys0,         // layer0 output bf16 [16384][2048]
    float* __restrict__ out,       // d_out
    u16* __restrict__ hbuf,        // [2 buf][2 dir][32][1024] bf16
    const int* __restrict__ lens,
    int* __restrict__ bar)         // 256 flag slots * 32 ints
{
    const int blk   = blockIdx.x;
    const int dir   = blk & 1;
    const int slice = blk >> 1;     // 0..127
    const int j0    = slice << 3;   // 8 h-units per block
    const int tid   = threadIdx.x;
    const int lane  = tid & 63;
    const int r15   = lane & 15;
    const int quad  = lane >> 4;
    const int wid   = tid >> 6;
    const int bt    = wid & 1;      // batch tile
    const int rt    = wid >> 1;     // gate-row tile

    __shared__ u16 Bl[32768];       // [f:32][rt:2][lane:64][8 u16] = 64 KB
    __shared__ float ghh[32][33];

    // ---- fill Bl once: Whh slice pre-swizzled into fragment order ----
    {
        const u16* wbase = Whh + ((size_t)(layer * 2 + dir) << 22);
#pragma unroll
        for (int it = 0; it < 16; ++it) {
            int idx = it * 256 + tid;            // (f*2+rt)*64 + lane
            int l  = idx & 63;
            int fr = (idx >> 6) & 1;
            int ff = idx >> 7;
            int q  = l >> 4;
            int r  = l & 15;
            int nl = fr * 16 + r;
            int rowg = ((nl >> 3) << 10) + j0 + (nl & 7);
            const u16* src = wbase + ((size_t)rowg << 10) + ff * 32 + q * 8;
            *(short8*)(Bl + idx * 8) = *(const short8*)src;
        }
    }

    const int ub = tid & 7;        // unit within slice
    const int bb = tid >> 3;       // batch 0..31
    const int gu = j0 + ub;        // global h-unit
    const int len_b = lens[bb];
    float hreg = 0.f, creg = 0.f;

    int* myflag   = bar + ((dir << 7) + slice) * 32;
    int* pollflag = bar + ((dir << 7) + (tid & 127)) * 32;

    const u32 bl_byte = (u32)(((rt << 6) + lane) << 4);  // byte offset within a 2KB f-stripe
    const int nloc = rt * 16 + r15;                      // local gate row 0..31

    // zero h_0 (buffer 0) for own units: write-through, then announce
    if ((ub & 1) == 0) {
        u32* hp = (u32*)(hbuf + (((size_t)dir) << 15) + ((size_t)bb << 10) + gu);
        __hip_atomic_store(hp, 0u, __ATOMIC_RELAXED, __HIP_MEMORY_SCOPE_AGENT);
    }
    asm volatile("s_waitcnt vmcnt(0)" ::: "memory");
    __syncthreads();   // also makes Bl fill visible block-wide
    if (tid == 0)
        __hip_atomic_store(myflag, pbase + 1, __ATOMIC_RELAXED, __HIP_MEMORY_SCOPE_AGENT);

    const u16* Gd = dir ? Gb : Gf;
    const int abase = (bt * 16 + r15) << 10;

    // prefetch gates for step 0 (s=0 is always valid: len >= 64)
    int pcur = dir ? (len_b - 1) : 0;
    const u16* gp0 = Gd + (((size_t)pcur << 5) + bb) * 4096 + gu;
    u16 gvi = gp0[0], gvf = gp0[1024], gvg = gp0[2048], gvo = gp0[3072];

    for (int s = 0; s < TT; ++s) {
        // wait until every block of this direction has published h_s.
        if (tid < 128) {
            const int target = pbase + s + 1;
            while (__hip_atomic_load(pollflag, __ATOMIC_RELAXED, __HIP_MEMORY_SCOPE_AGENT) < target)
                __builtin_amdgcn_s_sleep(1);
        }
        __syncthreads();

        const u16* hb = hbuf + (((size_t)((s & 1) * 2 + dir)) << 15) + abase;

        f32x4 acc[4];
#pragma unroll
        for (int q2 = 0; q2 < 4; ++q2) acc[q2] = (f32x4){0.f, 0.f, 0.f, 0.f};

        // A from L3 (pipelined), B from LDS (conflict-free ds_read_b128)
        short8 a0[8], a1[8];
        LOADC(a0, 0);
        LOADC(a1, 8);
        MFMA8B(a0, 0);
        LOADC(a0, 16);
        MFMA8B(a1, 8);
        LOADC(a1, 24);
        MFMA8B(a0, 16);
        MFMA8B(a1, 24);

        f32x4 ac = (acc[0] + acc[1]) + (acc[2] + acc[3]);
#pragma unroll
        for (int r = 0; r < 4; ++r)
            ghh[bt * 16 + quad * 4 + r][nloc] = ac[r];
        __syncthreads();

        float gi  = ghh[bb][ub]      + bf2f(gvi);
        float gf_ = ghh[bb][8 + ub]  + bf2f(gvf);
        float gg  = ghh[bb][16 + ub] + bf2f(gvg);
        float go  = ghh[bb][24 + ub] + bf2f(gvo);
        float si = 1.f / (1.f + __expf(-gi));
        float sf = 1.f / (1.f + __expf(-gf_));
        float sg = ftanh(gg);
        float so = 1.f / (1.f + __expf(-go));
        float cn = sf * creg + si * sg;
        float hn = so * ftanh(cn);
        bool valid = (s < len_b);
        if (valid) { creg = cn; hreg = hn; }

        // publish h_{s+1}: lane-paired u32, write-through to coherent point
        u32 hv = (u32)f2bf(hreg);
        u32 pv = (u32)__shfl_xor((int)hv, 1);
        if ((ub & 1) == 0) {
            u32 pk = hv | (pv << 16);
            u32* hp = (u32*)(hbuf + (((size_t)(((s + 1) & 1) * 2 + dir)) << 15)
                             + ((size_t)bb << 10) + gu);
            __hip_atomic_store(hp, pk, __ATOMIC_RELAXED, __HIP_MEMORY_SCOPE_AGENT);
        }
        asm volatile("s_waitcnt vmcnt(0)" ::: "memory");
        __syncthreads();
        if (tid == 0)
            __hip_atomic_store(myflag, pbase + s + 2, __ATOMIC_RELAXED, __HIP_MEMORY_SCOPE_AGENT);

        // ---- y-store (off critical path, after flag) ----
        float yv = valid ? hn : 0.f;
        size_t yoff = (((size_t)pcur << 5) + bb) * 2048 + ((size_t)dir << 10) + gu;
        if (layer == 0) ys0[yoff] = f2bf(yv);
        else            out[yoff] = yv;

        // ---- prefetch gates for s+1: in flight during the next poll ----
        int sn = s + 1;
        if (sn < TT) {
            int pn = dir ? ((sn < len_b) ? (len_b - 1 - sn) : sn) : sn;
            const u16* gp = Gd + (((size_t)pn << 5) + bb) * 4096 + gu;
            gvi = gp[0]; gvf = gp[1024]; gvg = gp[2048]; gvo = gp[3072];
            pcur = pn;
        }
    }

    size_t hoff = (size_t)TT * BB_ * 2048 + (((size_t)(layer * 2 + dir) << 5) + bb) * 1024 + gu;
    out[hoff] = hreg;
    out[hoff + 4 * BB_ * HH] = creg;
}

// ---------------- host ----------------
extern "C" void kernel_launch(void* const* d_in, const int* in_sizes, int n_in,
                              void* d_out, int out_size, void* d_ws, size_t ws_size,
                              hipStream_t stream)
{
    const float* x    = (const float*)d_in[0];
    const unsigned char* mask = (const unsigned char*)d_in[1];
    const float* Wih  = (const float*)d_in[2];
    const float* Whh  = (const float*)d_in[3];
    const float* bih  = (const float*)d_in[4];
    const float* bhh  = (const float*)d_in[5];
    float* out = (float*)d_out;

    char* w = (char*)d_ws;
    size_t off = 0;
    auto take = [&](size_t bytes) {
        char* p = w + off;
        off = (off + bytes + 255) & ~(size_t)255;
        return p;
    };
    u16* xbf    = (u16*)take((size_t)33554432 * 2);   // x bf16; ALIASED as ys0 after layer-0 GEMMs
    u16* ysbf   = xbf;
    u16* wslice = (u16*)take((size_t)8388608 * 2);    // one Wih slice bf16, reused 4x
    u16* whhbf  = (u16*)take((size_t)16777216 * 2);   // Whh bf16
    u16* gf     = (u16*)take((size_t)67108864 * 2);   // gates fwd bf16
    u16* gb     = (u16*)take((size_t)67108864 * 2);   // gates bwd bf16
    u16* hbuf   = (u16*)take((size_t)131072 * 2);
    int* lens   = (int*)take(1024);
    int* bar    = (int*)take(65536);                  // 256 flags * 128 B

    f2bf_k<<<2048, 256, 0, stream>>>(x,   xbf,   33554432);
    f2bf_k<<<2048, 256, 0, stream>>>(Whh, whhbf, 16777216);
    prep<<<1, 256, 0, stream>>>(mask, lens, bar);

    dim3 gg(32, 128);
    for (int l = 0; l < 2; ++l) {
        const u16* X = l ? ysbf : xbf;
        for (int d = 0; d < 2; ++d) {
            f2bf_k<<<1024, 256, 0, stream>>>(Wih + (size_t)(l * 2 + d) * 4096 * 2048,
                                             wslice, 8388608);
            gemm_xw<<<gg, 256, 0, stream>>>(X, wslice,
                                            bih + (l * 2 + d) * 4096,
                                            bhh + (l * 2 + d) * 4096,
                                            d ? gb : gf);
        }
        int layer = l;
        int pbase = l * (TT + 1);
        void* args[] = { &layer, &pbase, (void*)&whhbf, (void*)&gf, (void*)&gb,
                         (void*)&ysbf, (void*)&out, (void*)&hbuf, (void*)&lens, (void*)&bar };
        hipLaunchCooperativeKernel((void*)lstm_layer, dim3(NBLK), dim3(256), args, 0, stream);
    }
    (void)in_sizes; (void)n_in; (void)out_size; (void)ws_size;
}

// Round 5
// 8254.020 us; speedup vs baseline: 1.6093x; 1.4896x over previous
//
#include <hip/hip_runtime.h>

typedef unsigned short u16;
typedef unsigned int u32;
typedef unsigned long long u64;
typedef __attribute__((ext_vector_type(8))) short short8;
typedef __attribute__((ext_vector_type(4))) float f32x4;
typedef __attribute__((ext_vector_type(4))) float f4v;
typedef __attribute__((ext_vector_type(4))) unsigned short us4v;

#define TT 512
#define BB_ 32
#define II 2048
#define HH 1024
#define HOLE 0xFFFFu

__device__ __forceinline__ u16 f2bf(float f) {
    u32 u = __float_as_uint(f);
    return (u16)((u + 0x7fffu + ((u >> 16) & 1u)) >> 16);
}
__device__ __forceinline__ float bf2f(u16 h) {
    return __uint_as_float(((u32)h) << 16);
}
__device__ __forceinline__ float ftanh(float x) {
    float e = __expf(2.f * x);
    return 1.f - 2.f / (e + 1.f);
}
__device__ __forceinline__ u64 aload(const u64* p) {
    return __hip_atomic_load(p, __ATOMIC_RELAXED, __HIP_MEMORY_SCOPE_AGENT);
}
__device__ __forceinline__ void astore32(u32* p, u32 v) {
    __hip_atomic_store(p, v, __ATOMIC_RELAXED, __HIP_MEMORY_SCOPE_AGENT);
}
__device__ __forceinline__ void astore64(u64* p, u64 v) {
    __hip_atomic_store(p, v, __ATOMIC_RELAXED, __HIP_MEMORY_SCOPE_AGENT);
}

// ---------------- fp32 -> bf16 conversion ----------------
__global__ __launch_bounds__(256) void f2bf_k(const float* __restrict__ s,
                                              u16* __restrict__ d, int n) {
    int i = (blockIdx.x * 256 + threadIdx.x) * 4;
    int stride = gridDim.x * 1024;
    for (; i < n; i += stride) {
        f4v v = *(const f4v*)(s + i);
        us4v o;
        o.x = f2bf(v.x); o.y = f2bf(v.y); o.z = f2bf(v.z); o.w = f2bf(v.w);
        *(us4v*)(d + i) = o;
    }
}

// ---------------- lens (dtype-robust mask read) ----------------
__global__ void prep(const unsigned char* __restrict__ mb, int* __restrict__ lens) {
    __shared__ int is8;
    int t = threadIdx.x;
    if (t == 0) is8 = 0;
    __syncthreads();
    for (int i = t; i < TT * BB_; i += 256) {
        if ((i & 3) && mb[i]) is8 = 1;   // benign race, same value
    }
    __syncthreads();
    int u8 = is8;
    if (t < BB_) {
        int c = 0;
        if (u8) {
            const unsigned char* r = mb + t * TT;
            for (int k = 0; k < TT; ++k) c += (r[k] == 0);
        } else {
            const int* r = (const int*)mb + t * TT;
            for (int k = 0; k < TT; ++k) c += (r[k] == 0);
        }
        c = (c < 0) ? 0 : (c > TT ? TT : c);
        lens[t] = c;
    }
}

// ---------------- hbuf init: [2 layer][4 buf][2 dir][32][1024] bf16 ----------------
// buf0 = 0.0 (valid h_0); buf1/2/3 = holes (no reliance on early-step holify).
__global__ __launch_bounds__(256) void hinit(u16* __restrict__ hbuf) {
    size_t i = (size_t)blockIdx.x * 256 + threadIdx.x;   // u64 index
    if (i < 65536) {
        size_t u16i = i * 4;
        int buf = (int)((u16i & 262143) >> 16);          // 0..3 within layer
        ((u64*)hbuf)[i] = (buf == 0) ? 0ull : 0xFFFFFFFFFFFFFFFFull;
    }
}

// ---------------- GEMM: G[m,n] = X[m,:] . W[n,:] + bi[n] + bh[n] ----------------
#define GM 16384
#define GN 4096
#define GK 2048

__device__ __forceinline__ void gload_lds16(const u16* g, u16* l) {
    __builtin_amdgcn_global_load_lds(
        (const __attribute__((address_space(1))) void*)g,
        (__attribute__((address_space(3))) void*)l, 16, 0, 0);
}

__global__ __launch_bounds__(256) void gemm_xw(
    const u16* __restrict__ X, const u16* __restrict__ W,
    const float* __restrict__ bi, const float* __restrict__ bh,
    u16* __restrict__ G)
{
    __shared__ u16 As[4096];
    __shared__ u16 Bs[4096];
    const int tid  = threadIdx.x;
    const int lane = tid & 63;
    const int r15  = lane & 15;
    const int quad = lane >> 4;
    const int wid  = tid >> 6;
    const int wr   = wid >> 1;
    const int wc   = wid & 1;
    const int m0   = blockIdx.y << 7;
    const int n0   = blockIdx.x << 7;

    f32x4 acc[4][4];
#pragma unroll
    for (int i = 0; i < 4; ++i)
#pragma unroll
        for (int j = 0; j < 4; ++j) acc[i][j] = (f32x4){0.f, 0.f, 0.f, 0.f};

    const int c0 = tid, c1 = 256 + tid;
    const int kq0 = c0 >> 7, row0 = c0 & 127;
    const int kq1 = c1 >> 7, row1 = c1 & 127;

    const u16* xA0 = X + (size_t)(m0 + row0) * GK + kq0 * 8;
    const u16* xA1 = X + (size_t)(m0 + row1) * GK + kq1 * 8;
    const u16* xB0 = W + (size_t)(n0 + row0) * GK + kq0 * 8;
    const u16* xB1 = W + (size_t)(n0 + row1) * GK + kq1 * 8;

    for (int kb = 0; kb < GK; kb += 32) {
        __syncthreads();
        gload_lds16(xA0 + kb, As + c0 * 8);
        gload_lds16(xA1 + kb, As + c1 * 8);
        gload_lds16(xB0 + kb, Bs + c0 * 8);
        gload_lds16(xB1 + kb, Bs + c1 * 8);
        __syncthreads();

        short8 a[4], b[4];
#pragma unroll
        for (int i = 0; i < 4; ++i)
            a[i] = *(const short8*)(As + (quad * 128 + wr * 64 + i * 16 + r15) * 8);
#pragma unroll
        for (int j = 0; j < 4; ++j)
            b[j] = *(const short8*)(Bs + (quad * 128 + wc * 64 + j * 16 + r15) * 8);
#pragma unroll
        for (int i = 0; i < 4; ++i)
#pragma unroll
            for (int j = 0; j < 4; ++j)
                acc[i][j] = __builtin_amdgcn_mfma_f32_16x16x32_bf16(a[i], b[j], acc[i][j], 0, 0, 0);
    }

#pragma unroll
    for (int j = 0; j < 4; ++j) {
        const int col = n0 + wc * 64 + j * 16 + r15;
        const float bias = bi[col] + bh[col];
#pragma unroll
        for (int i = 0; i < 4; ++i) {
            const int row = m0 + wr * 64 + i * 16 + quad * 4;
#pragma unroll
            for (int r = 0; r < 4; ++r)
                G[(size_t)(row + r) * GN + col] = f2bf(acc[i][j][r] + bias);
        }
    }
}

// ---------------- persistent LSTM layer: flagless hole-tagged dataflow ----------------
// 128 blocks x 512 thr; block (dir, slice) owns 16 h-units (64 gate rows).
// hbuf: depth-4 per (layer,dir); every 8B half-chunk self-validates via its
// first u16 (0xFFFF = hole; real h is tanh-bounded -> never 0xFFFF).
// Consumers poll data directly per 128-unit k-group, stage into LDS ping-pong,
// MFMA against LDS-resident Whh.  No flags, no bulk producer barrier.
// EVERY spin loop contains s_sleep(1): side-effecting intrinsic -> compiler
// cannot merge/hoist the relaxed atomic loads (r4 hang suspect).
#define NBLK 128

__global__ __launch_bounds__(512, 1) void lstm_layer(
    int layer,
    const u16* __restrict__ Whh,   // [4][4096][1024] bf16
    const u16* __restrict__ Gf,    // [16384][4096] bf16
    const u16* __restrict__ Gb,
    u16* __restrict__ ys0,         // layer0 output bf16 [16384][2048]
    float* __restrict__ out,       // d_out
    u16* __restrict__ hbuf,
    const int* __restrict__ lens)
{
    const int blk   = blockIdx.x;
    const int dir   = blk & 1;
    const int slice = blk >> 1;     // 0..63
    const int j0    = slice << 4;   // 16 h-units per block
    const int tid   = threadIdx.x;
    const int lane  = tid & 63;
    const int r15   = lane & 15;
    const int quad  = lane >> 4;
    const int wid   = tid >> 6;     // 0..7
    const int mt    = wid & 1;      // batch tile
    const int nt    = wid >> 1;     // gate tile (== gate index)

    __shared__ u16 Bl[65536];       // Whh frags: [kf:32][nt:4][lane:64][8 u16] = 128 KB
    __shared__ char Apg[16384];     // A ping-pong 2 x [kfl:4][b:32][64B]; ghh/hls aliased
    float* ghh = (float*)Apg;               // [4 gate][32 b][16 u]  (aliases ping0, safe)
    u16*   hls = (u16*)(Apg + 8192);        // [32 b][16 u]          (aliases ping1, safe)

    // ---- fill Bl once (pre-swizzled fragment order) ----
    {
        const u16* wdir = Whh + ((size_t)(layer * 2 + dir) << 22);
#pragma unroll
        for (int it = 0; it < 16; ++it) {
            int idx = it * 512 + tid;               // (kf*4+nt)*64 + l
            int kf = idx >> 8, n2 = (idx >> 6) & 3, l = idx & 63;
            const u16* src = wdir + (size_t)(n2 * 1024 + j0 + (l & 15)) * 1024
                                  + kf * 32 + (l >> 4) * 8;
            *(short8*)(Bl + idx * 8) = *(const short8*)src;
        }
    }

    const int ub = tid & 15;       // unit within slice
    const int bb = tid >> 4;       // batch 0..31
    const int gu = j0 + ub;        // global h-unit
    const int len_b = lens[bb];
    float hreg = 0.f, creg = 0.f;

    u16* hregion = hbuf + ((size_t)layer << 18);   // 4buf*2dir*32768 u16 per layer

    const u16* Gd = dir ? Gb : Gf;
    int pcur = dir ? (len_b - 1) : 0;
    const u16* gp0 = Gd + ((size_t)pcur * 32 + bb) * 4096 + gu;
    u16 gvi = gp0[0], gvf = gp0[1024], gvg = gp0[2048], gvo = gp0[3072];

    // staging map: thread -> (batch sb, kf-in-group kfl, quad sq) : one 16B chunk
    const int sb  = tid >> 4;
    const int kfl = (tid & 15) >> 2;
    const int sq  = tid & 3;

    __syncthreads();  // Bl ready (block-local)

    for (int s = 0; s < TT; ++s) {
        const char* rplane = (const char*)(hregion + (size_t)(((s & 3) * 2 + dir)) * 32768);
        u16* wplane = hregion + (size_t)((((s + 1) & 3) * 2 + dir)) * 32768;
        u16* hplane = hregion + (size_t)((((s + 2) & 3) * 2 + dir)) * 32768;

        // ---- holify own chunks of buf[s+2] (wave 0 only: ordered vs publish) ----
        if (tid < 64) {
            int b = tid >> 1, c = tid & 1;
            u32* tp = (u32*)(hplane + (size_t)b * 1024 + slice * 16 + c * 8);
            astore32(tp, 0xFFFFFFFFu);
            astore32(tp + 2, 0xFFFFFFFFu);
        }

        // ---- prologue: stage k-group 0 ----
        const u64* sp = (const u64*)(rplane + sb * 2048 + kfl * 64 + sq * 16);
        u64 lo = aload(sp), hi = aload(sp + 1);
        while ((u16)lo == HOLE || (u16)hi == HOLE) {
            __builtin_amdgcn_s_sleep(1);
            lo = aload(sp); hi = aload(sp + 1);
        }
        { union { u64 q[2]; short8 v; } uu; uu.q[0] = lo; uu.q[1] = hi;
          *(short8*)(Apg + (kfl * 32 + sb) * 64 + sq * 16) = uu.v; }
        __syncthreads();

        f32x4 acc[4];
#pragma unroll
        for (int i = 0; i < 4; ++i) acc[i] = (f32x4){0.f, 0.f, 0.f, 0.f};

        for (int g = 0; g < 8; ++g) {
            const u64* np = (const u64*)(rplane + sb * 2048 + ((g + 1) * 4 + kfl) * 64 + sq * 16);
            if (g < 7) { lo = aload(np); hi = aload(np + 1); }   // in flight during MFMA

            const char* abase = Apg + (g & 1) * 8192;
#pragma unroll
            for (int i = 0; i < 4; ++i) {
                short8 a = *(const short8*)(abase + (i * 32 + mt * 16 + r15) * 64 + quad * 16);
                short8 b = *(const short8*)((const char*)Bl + (((g * 4 + i) * 4 + nt) * 64 + lane) * 16);
                acc[i] = __builtin_amdgcn_mfma_f32_16x16x32_bf16(a, b, acc[i], 0, 0, 0);
            }

            if (g < 7) {
                while ((u16)lo == HOLE || (u16)hi == HOLE) {
                    __builtin_amdgcn_s_sleep(1);
                    lo = aload(np); hi = aload(np + 1);
                }
                union { u64 q[2]; short8 v; } uu; uu.q[0] = lo; uu.q[1] = hi;
                *(short8*)(Apg + ((g + 1) & 1) * 8192 + (kfl * 32 + sb) * 64 + sq * 16) = uu.v;
            }
            __syncthreads();
        }

        // ---- gate pre-acts -> ghh (aliases ping0; all ping reads retired) ----
        f32x4 ac = (acc[0] + acc[1]) + (acc[2] + acc[3]);
#pragma unroll
        for (int r = 0; r < 4; ++r)
            ghh[(nt * 32 + mt * 16 + quad * 4 + r) * 16 + r15] = ac[r];
        __syncthreads();

        // ---- elementwise: thread owns (batch bb, unit ub) ----
        float gi  = ghh[(0 * 32 + bb) * 16 + ub] + bf2f(gvi);
        float gf_ = ghh[(1 * 32 + bb) * 16 + ub] + bf2f(gvf);
        float gg  = ghh[(2 * 32 + bb) * 16 + ub] + bf2f(gvg);
        float go  = ghh[(3 * 32 + bb) * 16 + ub] + bf2f(gvo);
        float si = 1.f / (1.f + __expf(-gi));
        float sf = 1.f / (1.f + __expf(-gf_));
        float sg = ftanh(gg);
        float so = 1.f / (1.f + __expf(-go));
        float cn = sf * creg + si * sg;
        float hn = so * ftanh(cn);
        bool valid = (s < len_b);
        if (valid) { creg = cn; hreg = hn; }

        hls[bb * 16 + ub] = f2bf(hreg);
        __syncthreads();

        // ---- publish h_{s+1} (wave 0): holify drained first, then tagged data ----
        if (tid < 64) {
            int b = tid >> 1, c = tid & 1;
            union { u64 q[2]; short8 v; } uu;
            uu.v = *(const short8*)(hls + b * 16 + c * 8);
            asm volatile("s_waitcnt vmcnt(0)" ::: "memory");   // holify globally visible
            u64* dp = (u64*)(wplane + (size_t)b * 1024 + slice * 16 + c * 8);
            astore64(dp, uu.q[0]);
            astore64(dp + 1, uu.q[1]);
        }

        // ---- y-store + gate prefetch (off critical path) ----
        float yv = valid ? hn : 0.f;
        size_t yoff = ((size_t)pcur * 32 + bb) * 2048 + ((size_t)dir << 10) + gu;
        if (layer == 0) ys0[yoff] = f2bf(yv);
        else            out[yoff] = yv;

        int sn = s + 1;
        if (sn < TT) {
            int pn = dir ? ((sn < len_b) ? (len_b - 1 - sn) : sn) : sn;
            const u16* gp = Gd + ((size_t)pn * 32 + bb) * 4096 + gu;
            gvi = gp[0]; gvf = gp[1024]; gvg = gp[2048]; gvo = gp[3072];
            pcur = pn;
        }
    }

    size_t hoff = (size_t)TT * BB_ * 2048 + (((size_t)(layer * 2 + dir) << 5) + bb) * 1024 + gu;
    out[hoff] = hreg;
    out[hoff + 4 * BB_ * HH] = creg;
}

// ---------------- host ----------------
extern "C" void kernel_launch(void* const* d_in, const int* in_sizes, int n_in,
                              void* d_out, int out_size, void* d_ws, size_t ws_size,
                              hipStream_t stream)
{
    const float* x    = (const float*)d_in[0];
    const unsigned char* mask = (const unsigned char*)d_in[1];
    const float* Wih  = (const float*)d_in[2];
    const float* Whh  = (const float*)d_in[3];
    const float* bih  = (const float*)d_in[4];
    const float* bhh  = (const float*)d_in[5];
    float* out = (float*)d_out;

    char* w = (char*)d_ws;
    size_t off = 0;
    auto take = [&](size_t bytes) {
        char* p = w + off;
        off = (off + bytes + 255) & ~(size_t)255;
        return p;
    };
    u16* xbf    = (u16*)take((size_t)33554432 * 2);   // x bf16; ALIASED as ys0 after layer-0 GEMMs
    u16* ysbf   = xbf;
    u16* wslice = (u16*)take((size_t)8388608 * 2);    // one Wih slice bf16, reused 4x
    u16* whhbf  = (u16*)take((size_t)16777216 * 2);   // Whh bf16
    u16* gf     = (u16*)take((size_t)67108864 * 2);   // gates fwd bf16
    u16* gb     = (u16*)take((size_t)67108864 * 2);   // gates bwd bf16
    u16* hbuf   = (u16*)take((size_t)524288 * 2);     // 2 layer x 4 buf x 2 dir x 32 x 1024
    int* lens   = (int*)take(1024);

    f2bf_k<<<2048, 256, 0, stream>>>(x,   xbf,   33554432);
    f2bf_k<<<2048, 256, 0, stream>>>(Whh, whhbf, 16777216);
    hinit<<<256, 256, 0, stream>>>(hbuf);
    prep<<<1, 256, 0, stream>>>(mask, lens);

    dim3 gg(32, 128);
    for (int l = 0; l < 2; ++l) {
        const u16* X = l ? ysbf : xbf;
        for (int d = 0; d < 2; ++d) {
            f2bf_k<<<1024, 256, 0, stream>>>(Wih + (size_t)(l * 2 + d) * 4096 * 2048,
                                             wslice, 8388608);
            gemm_xw<<<gg, 256, 0, stream>>>(X, wslice,
                                            bih + (l * 2 + d) * 4096,
                                            bhh + (l * 2 + d) * 4096,
                                            d ? gb : gf);
        }
        int layer = l;
        void* args[] = { &layer, (void*)&whhbf, (void*)&gf, (void*)&gb,
                         (void*)&ysbf, (void*)&out, (void*)&hbuf, (void*)&lens };
        hipLaunchCooperativeKernel((void*)lstm_layer, dim3(NBLK), dim3(512), args, 0, stream);
    }
    (void)in_sizes; (void)n_in; (void)out_size; (void)ws_size;
}